// Round 13
// baseline (100.680 us; speedup 1.0000x reference)
//
#include <hip/hip_runtime.h>

// Problem constants (B,T,C,H) = (8, 2048, 1024, 128)
constexpr int Bz = 8, Tt = 2048, Cc = 1024, Hh = 128;
constexpr int Mrows = Bz * Tt;                 // 16384
constexpr float kScale = 0.08838834764831843f; // 1/sqrt(128)

typedef float f32x4 __attribute__((ext_vector_type(4)));
typedef short s16x8 __attribute__((ext_vector_type(8)));
typedef short s16x4 __attribute__((ext_vector_type(4)));
typedef unsigned short u16;

static __device__ __forceinline__ u16 f2bf(float f) {
    union { float f; unsigned int u; } c; c.f = f;
    unsigned int u = c.u;
    unsigned int r = (u + 0x7fffu + ((u >> 16) & 1u)) >> 16;   // RNE
    return (u16)r;
}
static __device__ __forceinline__ float bf2f(u16 x) {
    union { unsigned int u; float f; } c; c.u = ((unsigned int)x) << 16;
    return c.f;
}

// ---------------------------------------------------------------------------
// Kernel 0: transpose+convert weights.
// ---------------------------------------------------------------------------
__global__ __launch_bounds__(256) void convw_kernel(
    const float* __restrict__ Wq, const float* __restrict__ Wk,
    const float* __restrict__ Wv, const float* __restrict__ Wp,
    u16* __restrict__ wt, u16* __restrict__ wpt)
{
    int i = blockIdx.x * 256 + threadIdx.x;      // < 409600
    if (i < 393216) {
        int z = i >> 17, r = i & 131071;
        int n = r >> 10, k = r & 1023;
        const float* W = (z == 0) ? Wq : (z == 1) ? Wk : Wv;
        wt[i] = f2bf(W[k * Hh + n]);
    } else {
        int r2 = i - 393216;                     // n*128 + k
        int n = r2 >> 7, k = r2 & 127;
        wpt[r2] = f2bf(Wp[k * Hh + n]);
    }
}

// ---------------------------------------------------------------------------
// Kernel 1: FUSED QKV GEMM — reads x ONCE; Q,K + V^T outputs.
// BM=32, BK=128, N=384.  256 threads (4 waves), grid 512 -> 2 blocks/CU
// (1 wave/SIMD each; two blocks interleave per SIMD and hide each other's
// staging stalls).  Double-buffered LDS A (2x8KB) -> ONE barrier per iter.
// Per wave-iter: 48 MFMA : 24 B-loads : 4 A-loads; A_{j+1} issued early,
// consumed (cvt+ds_write) after the MFMA wall.
// ---------------------------------------------------------------------------
__global__ __launch_bounds__(256, 2)
void qkv_fused(
    const float* __restrict__ x, const u16* __restrict__ wt,
    u16* __restrict__ qo, u16* __restrict__ ko, u16* __restrict__ vt)
{
    __shared__ __align__(16) u16 as[2][32 * 128];   // 16 KB double-buffered

    const int tid  = threadIdx.x;
    const int m0   = blockIdx.x * 32;
    const int lane = tid & 63, wid = tid >> 6;   // wid 0..3
    const int l15  = lane & 15, l4 = lane >> 4;
    const int bb   = m0 >> 11;                   // batch
    const int t0   = m0 & 2047;                  // seq offset within batch

    // A staging ownership: 4 float4/thread (1024 granules of 4 floats)
    const int m_s  = tid >> 3;                   // row 0..31
    const int c4_s = (tid & 7) * 4;              // float4 col base 0..28 step 4

    f32x4 acc[2][6];
#pragma unroll
    for (int mi = 0; mi < 2; ++mi)
#pragma unroll
        for (int ni = 0; ni < 6; ++ni) {
            f32x4 z4 = {0.f, 0.f, 0.f, 0.f};
            acc[mi][ni] = z4;
        }

    // ---- prologue: stage A_0 into buf0 ----
#pragma unroll
    for (int u = 0; u < 4; ++u) {
        int kf4 = (c4_s + u * 32) * 4 % 128;     // u covers 4 chunks of 32 cols
        int kcol = (tid & 7) * 4 + u * 32;       // 0..127 in steps
        float4 xv = *reinterpret_cast<const float4*>(
            &x[(size_t)(m0 + m_s) * Cc + kcol * 1]);
        s16x4 bv;
        bv[0] = (short)f2bf(xv.x); bv[1] = (short)f2bf(xv.y);
        bv[2] = (short)f2bf(xv.z); bv[3] = (short)f2bf(xv.w);
        *reinterpret_cast<s16x4*>(
            &as[0][m_s * 128 + (kcol ^ ((m_s & 7) << 3))]) = bv;
        (void)kf4;
    }

    for (int j = 0; j < 8; ++j) {
        const int buf = j & 1;
        const int k0 = j * 128;
        __syncthreads();                         // buf ready; prior reads done

        // A fragments from LDS: af[2][4]
        s16x8 af[2][4];
#pragma unroll
        for (int mi = 0; mi < 2; ++mi) {
            int r = mi * 16 + l15;
#pragma unroll
            for (int ks = 0; ks < 4; ++ks)
                af[mi][ks] = *reinterpret_cast<const s16x8*>(
                    &as[buf][r * 128 + ((ks * 32 + l4 * 8) ^ ((r & 7) << 3))]);
        }

        // issue A_{j+1} early (HBM latency hides under B-wait + MFMA wall)
        float4 a_next[4];
        if (j < 7) {
#pragma unroll
            for (int u = 0; u < 4; ++u) {
                int kcol = (tid & 7) * 4 + u * 32;
                a_next[u] = *reinterpret_cast<const float4*>(
                    &x[(size_t)(m0 + m_s) * Cc + k0 + 128 + kcol]);
            }
        }

        // B fragments: 6 col-groups x 4 ks, direct from L2-resident wt
        s16x8 bfr[6][4];
#pragma unroll
        for (int ni = 0; ni < 6; ++ni) {
            int c = wid * 96 + ni * 16;
            int z = c >> 7, nloc = (c & 127) + l15;
            const u16* wb = wt + (size_t)z * 131072 + (size_t)nloc * 1024 + k0;
#pragma unroll
            for (int ks = 0; ks < 4; ++ks)
                bfr[ni][ks] = *reinterpret_cast<const s16x8*>(&wb[ks * 32 + l4 * 8]);
        }

        // MFMA wall: 48
#pragma unroll
        for (int mi = 0; mi < 2; ++mi)
#pragma unroll
            for (int ni = 0; ni < 6; ++ni)
#pragma unroll
                for (int ks = 0; ks < 4; ++ks)
                    acc[mi][ni] = __builtin_amdgcn_mfma_f32_16x16x32_bf16(
                        af[mi][ks], bfr[ni][ks], acc[mi][ni], 0, 0, 0);

        // consume A_{j+1}: cvt + write to other buffer
        if (j < 7) {
#pragma unroll
            for (int u = 0; u < 4; ++u) {
                int kcol = (tid & 7) * 4 + u * 32;
                s16x4 bv;
                bv[0] = (short)f2bf(a_next[u].x); bv[1] = (short)f2bf(a_next[u].y);
                bv[2] = (short)f2bf(a_next[u].z); bv[3] = (short)f2bf(a_next[u].w);
                *reinterpret_cast<s16x4*>(
                    &as[buf ^ 1][m_s * 128 + (kcol ^ ((m_s & 7) << 3))]) = bv;
            }
        }
    }

    // epilogue
#pragma unroll
    for (int mi = 0; mi < 2; ++mi)
#pragma unroll
        for (int ni = 0; ni < 6; ++ni) {
            int c = wid * 96 + ni * 16;
            int z = c >> 7, colz = (c & 127) + l15;
            if (z < 2) {
                u16* outp = (z == 0) ? qo : ko;
#pragma unroll
                for (int r = 0; r < 4; ++r) {
                    int row = m0 + mi * 16 + l4 * 4 + r;
                    outp[(size_t)row * Hh + colz] = f2bf(acc[mi][ni][r]);
                }
            } else {
                int trow = t0 + mi * 16 + l4 * 4;
                s16x4 pk;
#pragma unroll
                for (int r = 0; r < 4; ++r) pk[r] = (short)f2bf(acc[mi][ni][r]);
                *reinterpret_cast<s16x4*>(
                    &vt[((size_t)bb * Hh + colz) * Tt + trow]) = pk;
            }
        }
}

// ---------------------------------------------------------------------------
// Kernel 2: flash attention with cross-block KV split (s=2).
// (verbatim round-11/12 version: passing, ~25-28 µs)
// ---------------------------------------------------------------------------
__global__ __launch_bounds__(256, 4)
void attn_kernel(
    const u16* __restrict__ q, const u16* __restrict__ k,
    const u16* __restrict__ vt,
    u16* __restrict__ Opart, float* __restrict__ Mp, float* __restrict__ Lp)
{
    __shared__ __align__(16) char arena[37888];
    u16* ksl = reinterpret_cast<u16*>(arena);              // 64x128 u16, 16 KB
    u16* vsl = reinterpret_cast<u16*>(arena + 16384);      // 128x64 u16, 16 KB
    u16* psl = reinterpret_cast<u16*>(arena + 32768);      // 4 x 16x40 u16, 5 KB
    float* Om  = reinterpret_cast<float*>(arena);          // [4][16][132] f32
    float* ml2 = reinterpret_cast<float*>(arena + 33792);  // [4][2][16] f32

    const int tid = threadIdx.x, lane = tid & 63, wid = tid >> 6;
    const int l15 = lane & 15, l4 = lane >> 4;
    const int wq = wid >> 1, half = wid & 1;
    const int bid = blockIdx.x;
    const int b = bid & 7;               // batch -> XCD pinning
    const int rest = bid >> 3;           // 0..127
    const int qt = 63 - (rest >> 1);     // heavy q-tiles first
    const int split = rest & 1;
    const int q0 = qt * 32;
    const int ntf = (qt + 2) >> 1;       // total kv-64 tiles for this q-tile
    const int lo = (ntf * split) >> 1;
    const int hi = (ntf * (split + 1)) >> 1;

    const u16* qb = q  + (size_t)b * Tt * Hh;
    const u16* kb = k  + (size_t)b * Tt * Hh;
    const u16* vb = vt + (size_t)b * Hh * Tt;

    const int qrow = q0 + wq * 16 + l15;
    s16x8 qf[4];
#pragma unroll
    for (int ks = 0; ks < 4; ++ks)
        qf[ks] = *reinterpret_cast<const s16x8*>(
            &qb[(size_t)qrow * Hh + ks * 32 + l4 * 8]);

    f32x4 o[8];
#pragma unroll
    for (int nh = 0; nh < 8; ++nh) { f32x4 z4 = {0.f,0.f,0.f,0.f}; o[nh] = z4; }
    float mreg = -1e30f, lreg = 0.f;

    const int kr_s  = tid >> 2, kc_s = (tid & 3) * 4;
    const int vh_s  = tid >> 1, vc_s = (tid & 1) * 4;
    u16* ps = psl + wid * 640;

    for (int j = lo; j < hi; ++j) {
        const int kv0 = j * 64;

#pragma unroll
        for (int i = 0; i < 4; ++i) {
            s16x8 tk = *reinterpret_cast<const s16x8*>(
                &kb[(size_t)(kv0 + kr_s) * Hh + (kc_s + i) * 8]);
            *reinterpret_cast<s16x8*>(
                &ksl[kr_s * 128 + (((kc_s + i) * 8) ^ ((kr_s & 7) << 3))]) = tk;
        }
#pragma unroll
        for (int i = 0; i < 4; ++i) {
            s16x8 tv = *reinterpret_cast<const s16x8*>(
                &vb[(size_t)vh_s * Tt + kv0 + (vc_s + i) * 8]);
            *reinterpret_cast<s16x8*>(
                &vsl[vh_s * 64 + (((vc_s + i) * 8) ^ ((vh_s & 7) << 3))]) = tv;
        }
        __syncthreads();

        f32x4 sacc[2];
#pragma unroll
        for (int nf = 0; nf < 2; ++nf) { f32x4 z4 = {0.f,0.f,0.f,0.f}; sacc[nf] = z4; }
#pragma unroll
        for (int nf = 0; nf < 2; ++nf) {
            const int kr = half * 32 + nf * 16 + l15;
#pragma unroll
            for (int ks = 0; ks < 4; ++ks) {
                s16x8 kfrag = *reinterpret_cast<const s16x8*>(
                    &ksl[kr * 128 + ((ks * 32 + l4 * 8) ^ ((kr & 7) << 3))]);
                sacc[nf] = __builtin_amdgcn_mfma_f32_16x16x32_bf16(
                    kfrag, qf[ks], sacc[nf], 0, 0, 0);
            }
        }

        const bool diag = (j == ntf - 1);
        float pv2[2][4];
#pragma unroll
        for (int nf = 0; nf < 2; ++nf)
#pragma unroll
            for (int r = 0; r < 4; ++r) {
                float s = sacc[nf][r] * kScale;
                if (diag) {
                    int kvg = kv0 + half * 32 + nf * 16 + l4 * 4 + r;
                    if (kvg > qrow) s = -1e30f;
                }
                pv2[nf][r] = s;
            }
        float mx = fmaxf(fmaxf(fmaxf(pv2[0][0], pv2[0][1]), fmaxf(pv2[0][2], pv2[0][3])),
                         fmaxf(fmaxf(pv2[1][0], pv2[1][1]), fmaxf(pv2[1][2], pv2[1][3])));
        mx = fmaxf(mx, __shfl_xor(mx, 16));
        mx = fmaxf(mx, __shfl_xor(mx, 32));
        const float mold = mreg;
        const float mnew = fmaxf(mold, mx);
        const float scl = __expf(mold - mnew);
        mreg = mnew;
        float rs = 0.f;
#pragma unroll
        for (int nf = 0; nf < 2; ++nf)
#pragma unroll
            for (int r = 0; r < 4; ++r) {
                float pp = __expf(pv2[nf][r] - mnew);
                pv2[nf][r] = pp; rs += pp;
            }
        rs += __shfl_xor(rs, 16);
        rs += __shfl_xor(rs, 32);
        lreg = lreg * scl + rs;

        if (!__all(mold == mnew)) {
            float sclr[4];
#pragma unroll
            for (int r = 0; r < 4; ++r) sclr[r] = __shfl(scl, l4 * 4 + r);
#pragma unroll
            for (int nh = 0; nh < 8; ++nh)
#pragma unroll
                for (int r = 0; r < 4; ++r) o[nh][r] *= sclr[r];
        }

#pragma unroll
        for (int nf = 0; nf < 2; ++nf) {
            s16x4 pk4;
#pragma unroll
            for (int r = 0; r < 4; ++r) pk4[r] = (short)f2bf(pv2[nf][r]);
            *reinterpret_cast<s16x4*>(&ps[l15 * 40 + nf * 16 + l4 * 4]) = pk4;
        }
        s16x8 pa = *reinterpret_cast<const s16x8*>(&ps[l15 * 40 + l4 * 8]);

#pragma unroll
        for (int nh = 0; nh < 8; ++nh) {
            const int hr = nh * 16 + l15;
            s16x8 vfrag = *reinterpret_cast<const s16x8*>(
                &vsl[hr * 64 + ((half * 32 + l4 * 8) ^ ((hr & 7) << 3))]);
            o[nh] = __builtin_amdgcn_mfma_f32_16x16x32_bf16(
                pa, vfrag, o[nh], 0, 0, 0);
        }
        __syncthreads();
    }

#pragma unroll
    for (int nh = 0; nh < 8; ++nh)
#pragma unroll
        for (int r = 0; r < 4; ++r)
            Om[((wid * 16) + l4 * 4 + r) * 132 + nh * 16 + l15] = o[nh][r];
    if (lane < 16) {
        ml2[wid * 32 + lane] = mreg;
        ml2[wid * 32 + 16 + lane] = lreg;
    }
    __syncthreads();

    {
        const int row = tid >> 3, ch = tid & 7;
        const int rg = row >> 4, r16 = row & 15;
        const int w0 = rg * 2, w1 = rg * 2 + 1;
        float m0v = ml2[w0 * 32 + r16], m1v = ml2[w1 * 32 + r16];
        float M = fmaxf(m0v, m1v);
        float f0 = __expf(m0v - M), f1 = __expf(m1v - M);
        float L = f0 * ml2[w0 * 32 + 16 + r16] + f1 * ml2[w1 * 32 + 16 + r16];
        const size_t gm = (size_t)b * Tt + q0 + row;
        union { u16 u[8]; s16x8 v; } pk0, pk1;
#pragma unroll
        for (int c = 0; c < 8; ++c) {
            float a = f0 * Om[(w0 * 16 + r16) * 132 + ch * 16 + c]
                    + f1 * Om[(w1 * 16 + r16) * 132 + ch * 16 + c];
            pk0.u[c] = f2bf(a);
        }
#pragma unroll
        for (int c = 0; c < 8; ++c) {
            float a = f0 * Om[(w0 * 16 + r16) * 132 + ch * 16 + 8 + c]
                    + f1 * Om[(w1 * 16 + r16) * 132 + ch * 16 + 8 + c];
            pk1.u[c] = f2bf(a);
        }
        u16* op = Opart + ((size_t)split * Mrows + gm) * 128 + ch * 16;
        *reinterpret_cast<s16x8*>(op) = pk0.v;
        *reinterpret_cast<s16x8*>(op + 8) = pk1.v;
        if (ch == 0) {
            Mp[split * Mrows + gm] = M;
            Lp[split * Mrows + gm] = L;
        }
    }
}

// ---------------------------------------------------------------------------
// Kernel 3: merge 2 KV-split partials + fused output projection + bias.
// (verbatim round-11/12 version)
// ---------------------------------------------------------------------------
__global__ __launch_bounds__(256) void merge_proj(
    const u16* __restrict__ Opart, const float* __restrict__ Mp,
    const float* __restrict__ Lp, const u16* __restrict__ wpt,
    const float* __restrict__ bp, float* __restrict__ O)
{
    __shared__ __align__(16) u16 pm[64 * 136];
    __shared__ float f0s[64], f1s[64], invs[64];

    const int tid = threadIdx.x, lane = tid & 63, wid = tid >> 6;
    const int l15 = lane & 15, l4 = lane >> 4;
    const int m0r = blockIdx.x * 64;

    if (tid < 64) {
        float m0v = Mp[m0r + tid], m1v = Mp[Mrows + m0r + tid];
        float M = fmaxf(m0v, m1v);
        float a0 = __expf(m0v - M), a1 = __expf(m1v - M);
        float L = a0 * Lp[m0r + tid] + a1 * Lp[Mrows + m0r + tid];
        f0s[tid] = a0; f1s[tid] = a1; invs[tid] = 1.f / L;
    }
    __syncthreads();

#pragma unroll
    for (int u = 0; u < 4; ++u) {
        int idx = tid + u * 256;
        int row = idx >> 4, g = idx & 15;
        const size_t base = (size_t)(m0r + row) * 128 + g * 8;
        s16x8 p0 = *reinterpret_cast<const s16x8*>(&Opart[base]);
        s16x8 p1 = *reinterpret_cast<const s16x8*>(
            &Opart[(size_t)Mrows * 128 + base]);
        float a0 = f0s[row], a1 = f1s[row], inv = invs[row];
        union { u16 u[8]; s16x8 v; } pk;
#pragma unroll
        for (int c = 0; c < 8; ++c) {
            float v0 = bf2f((u16)p0[c]), v1 = bf2f((u16)p1[c]);
            pk.u[c] = f2bf((a0 * v0 + a1 * v1) * inv);
        }
        *reinterpret_cast<s16x8*>(&pm[row * 136 + g * 8]) = pk.v;
    }
    __syncthreads();

    {
        const int row2 = wid * 16 + l15;
        s16x8 af2[4];
#pragma unroll
        for (int ks = 0; ks < 4; ++ks)
            af2[ks] = *reinterpret_cast<const s16x8*>(
                &pm[row2 * 136 + ks * 32 + l4 * 8]);
#pragma unroll
        for (int ng = 0; ng < 8; ++ng) {
            const int ncol = ng * 16 + l15;
            f32x4 pacc = {0.f, 0.f, 0.f, 0.f};
#pragma unroll
            for (int ks = 0; ks < 4; ++ks) {
                s16x8 wf = *reinterpret_cast<const s16x8*>(
                    &wpt[(size_t)ncol * 128 + ks * 32 + l4 * 8]);
                pacc = __builtin_amdgcn_mfma_f32_16x16x32_bf16(
                    af2[ks], wf, pacc, 0, 0, 0);
            }
            float bias = bp[ncol];
#pragma unroll
            for (int r = 0; r < 4; ++r)
                O[(size_t)(m0r + wid * 16 + l4 * 4 + r) * Hh + ncol] =
                    pacc[r] + bias;
        }
    }
}

// ---------------------------------------------------------------------------
extern "C" void kernel_launch(void* const* d_in, const int* in_sizes, int n_in,
                              void* d_out, int out_size, void* d_ws, size_t ws_size,
                              hipStream_t stream) {
    const float* x  = (const float*)d_in[0];
    const float* Wk = (const float*)d_in[1];
    const float* Wq = (const float*)d_in[2];
    const float* Wv = (const float*)d_in[3];
    const float* Wp = (const float*)d_in[4];
    const float* bp = (const float*)d_in[5];
    float* out = (float*)d_out;

    // workspace (u16): wt 393216 | wpt 16384 | qw 2M | kw 2M | vt 2M |
    //                  Opart 2x2M | Mp,Lp f32 2x16384 each   (~22.1 MB)
    u16* wtb = (u16*)d_ws;
    u16* wpt = wtb + 393216;
    u16* qw  = wpt + 16384;
    u16* kw  = qw + (size_t)Mrows * Hh;
    u16* vtb = kw + (size_t)Mrows * Hh;
    u16* opart = vtb + (size_t)Mrows * Hh;
    float* Mpart = (float*)(opart + (size_t)2 * Mrows * Hh);
    float* Lpart = Mpart + 2 * Mrows;

    convw_kernel<<<1600, 256, 0, stream>>>(Wq, Wk, Wv, Wp, wtb, wpt);
    qkv_fused<<<Mrows / 32, 256, 0, stream>>>(x, wtb, qw, kw, vtb);
    attn_kernel<<<1024, 256, 0, stream>>>(qw, kw, vtb, opart, Mpart, Lpart);
    merge_proj<<<Mrows / 64, 256, 0, stream>>>(opart, Mpart, Lpart, wpt, bp, out);
}

// Round 14
// 80.129 us; speedup vs baseline: 1.2565x; 1.2565x over previous
//
#include <hip/hip_runtime.h>

// Problem constants (B,T,C,H) = (8, 2048, 1024, 128)
constexpr int Bz = 8, Tt = 2048, Cc = 1024, Hh = 128;
constexpr int Mrows = Bz * Tt;                 // 16384
constexpr float kScale = 0.08838834764831843f; // 1/sqrt(128)

typedef float f32x4 __attribute__((ext_vector_type(4)));
typedef short s16x8 __attribute__((ext_vector_type(8)));
typedef short s16x4 __attribute__((ext_vector_type(4)));
typedef unsigned short u16;

static __device__ __forceinline__ u16 f2bf(float f) {
    union { float f; unsigned int u; } c; c.f = f;
    unsigned int u = c.u;
    unsigned int r = (u + 0x7fffu + ((u >> 16) & 1u)) >> 16;   // RNE
    return (u16)r;
}
static __device__ __forceinline__ float bf2f(u16 x) {
    union { unsigned int u; float f; } c; c.u = ((unsigned int)x) << 16;
    return c.f;
}

// ---------------------------------------------------------------------------
// Kernel 0: transpose+convert weights.
// ---------------------------------------------------------------------------
__global__ __launch_bounds__(256) void convw_kernel(
    const float* __restrict__ Wq, const float* __restrict__ Wk,
    const float* __restrict__ Wv, const float* __restrict__ Wp,
    u16* __restrict__ wt, u16* __restrict__ wpt)
{
    int i = blockIdx.x * 256 + threadIdx.x;      // < 409600
    if (i < 393216) {
        int z = i >> 17, r = i & 131071;
        int n = r >> 10, k = r & 1023;
        const float* W = (z == 0) ? Wq : (z == 1) ? Wk : Wv;
        wt[i] = f2bf(W[k * Hh + n]);
    } else {
        int r2 = i - 393216;                     // n*128 + k
        int n = r2 >> 7, k = r2 & 127;
        wpt[r2] = f2bf(Wp[k * Hh + n]);
    }
}

// ---------------------------------------------------------------------------
// Kernel 1: QKV GEMM, N-SPLIT grid for co-residency.
// grid = (256,1,3): block (bx,z) computes output z (0=Q,1=K,2=V^T) cols 0..127
// for rows bx*64 -> 768 blocks = 3 blocks/CU; co-resident blocks overlap each
// other's staging stalls and barrier drains (the mechanism that fixed attn).
// BM=64, BK=64, 256 threads (4 waves), wave tile 64x32: acc[4][2] (32 VGPR,
// no regalloc squeeze), 16 MFMA : 4 B-loads per wave-iter, B pre-barrier.
// A tile re-read 3x lands on the SAME XCD (bids bx, bx+256, bx+512 ≡ mod 8)
// -> L2 absorbs; x HBM traffic stays ~67 MB.
// ---------------------------------------------------------------------------
__global__ __launch_bounds__(256, 3)
void qkv_fused(
    const float* __restrict__ x, const u16* __restrict__ wt,
    u16* __restrict__ qo, u16* __restrict__ ko, u16* __restrict__ vt)
{
    __shared__ __align__(16) u16 as[64 * 64];    // 8 KB

    const int tid  = threadIdx.x;
    const int m0   = blockIdx.x * 64;
    const int z    = blockIdx.z;                 // 0=Q, 1=K, 2=V^T
    const int lane = tid & 63, wid = tid >> 6;   // wid 0..3
    const int l15  = lane & 15, l4 = lane >> 4;
    const int bb   = m0 >> 11;                   // batch
    const int t0   = m0 & 2047;                  // seq offset within batch

    const u16* wz = wt + (size_t)z * 131072;

    f32x4 acc[4][2];
#pragma unroll
    for (int mi = 0; mi < 4; ++mi)
#pragma unroll
        for (int ni = 0; ni < 2; ++ni) {
            f32x4 z4 = {0.f, 0.f, 0.f, 0.f};
            acc[mi][ni] = z4;
        }

    for (int k0 = 0; k0 < Cc; k0 += 64) {
        // stage A: 64x64 fp32 -> bf16 swizzled (1024 float4, 4/thread)
#pragma unroll
        for (int u = 0; u < 4; ++u) {
            int idx = tid + u * 256;
            int m = idx >> 4, kf4 = (idx & 15) * 4;
            float4 xv = *reinterpret_cast<const float4*>(
                &x[(size_t)(m0 + m) * Cc + k0 + kf4]);
            s16x4 bv;
            bv[0] = (short)f2bf(xv.x); bv[1] = (short)f2bf(xv.y);
            bv[2] = (short)f2bf(xv.z); bv[3] = (short)f2bf(xv.w);
            *reinterpret_cast<s16x4*>(&as[m * 64 + (kf4 ^ ((m & 7) << 3))]) = bv;
        }
        // B fragments issued pre-barrier (latency absorbed by barrier drain)
        s16x8 bfr[2][2];
#pragma unroll
        for (int ni = 0; ni < 2; ++ni) {
            int nloc = wid * 32 + ni * 16 + l15;     // 0..127
            const u16* wb = wz + (size_t)nloc * 1024 + k0;
#pragma unroll
            for (int ks = 0; ks < 2; ++ks)
                bfr[ni][ks] = *reinterpret_cast<const s16x8*>(&wb[ks * 32 + l4 * 8]);
        }
        __syncthreads();

        s16x8 af[4][2];
#pragma unroll
        for (int mi = 0; mi < 4; ++mi) {
            int r = mi * 16 + l15;
#pragma unroll
            for (int ks = 0; ks < 2; ++ks)
                af[mi][ks] = *reinterpret_cast<const s16x8*>(
                    &as[r * 64 + ((ks * 32 + l4 * 8) ^ ((r & 7) << 3))]);
        }
#pragma unroll
        for (int mi = 0; mi < 4; ++mi)
#pragma unroll
            for (int ni = 0; ni < 2; ++ni)
#pragma unroll
                for (int ks = 0; ks < 2; ++ks)
                    acc[mi][ni] = __builtin_amdgcn_mfma_f32_16x16x32_bf16(
                        af[mi][ks], bfr[ni][ks], acc[mi][ni], 0, 0, 0);
        __syncthreads();
    }

    // epilogue (single-purpose per z)
#pragma unroll
    for (int mi = 0; mi < 4; ++mi)
#pragma unroll
        for (int ni = 0; ni < 2; ++ni) {
            int colz = wid * 32 + ni * 16 + l15;
            if (z < 2) {
                u16* outp = (z == 0) ? qo : ko;
#pragma unroll
                for (int r = 0; r < 4; ++r) {
                    int row = m0 + mi * 16 + l4 * 4 + r;
                    outp[(size_t)row * Hh + colz] = f2bf(acc[mi][ni][r]);
                }
            } else {
                // V^T: vt[b][h][t], 4 consecutive t -> one 8B store
                int trow = t0 + mi * 16 + l4 * 4;
                s16x4 pk;
#pragma unroll
                for (int r = 0; r < 4; ++r) pk[r] = (short)f2bf(acc[mi][ni][r]);
                *reinterpret_cast<s16x4*>(
                    &vt[((size_t)bb * Hh + colz) * Tt + trow]) = pk;
            }
        }
}

// ---------------------------------------------------------------------------
// Kernel 2: flash attention with cross-block KV split (s=2).
// (verbatim round-11/12/13 version: passing, ~25-28 µs)
// ---------------------------------------------------------------------------
__global__ __launch_bounds__(256, 4)
void attn_kernel(
    const u16* __restrict__ q, const u16* __restrict__ k,
    const u16* __restrict__ vt,
    u16* __restrict__ Opart, float* __restrict__ Mp, float* __restrict__ Lp)
{
    __shared__ __align__(16) char arena[37888];
    u16* ksl = reinterpret_cast<u16*>(arena);              // 64x128 u16, 16 KB
    u16* vsl = reinterpret_cast<u16*>(arena + 16384);      // 128x64 u16, 16 KB
    u16* psl = reinterpret_cast<u16*>(arena + 32768);      // 4 x 16x40 u16, 5 KB
    float* Om  = reinterpret_cast<float*>(arena);          // [4][16][132] f32
    float* ml2 = reinterpret_cast<float*>(arena + 33792);  // [4][2][16] f32

    const int tid = threadIdx.x, lane = tid & 63, wid = tid >> 6;
    const int l15 = lane & 15, l4 = lane >> 4;
    const int wq = wid >> 1, half = wid & 1;
    const int bid = blockIdx.x;
    const int b = bid & 7;               // batch -> XCD pinning
    const int rest = bid >> 3;           // 0..127
    const int qt = 63 - (rest >> 1);     // heavy q-tiles first
    const int split = rest & 1;
    const int q0 = qt * 32;
    const int ntf = (qt + 2) >> 1;       // total kv-64 tiles for this q-tile
    const int lo = (ntf * split) >> 1;
    const int hi = (ntf * (split + 1)) >> 1;

    const u16* qb = q  + (size_t)b * Tt * Hh;
    const u16* kb = k  + (size_t)b * Tt * Hh;
    const u16* vb = vt + (size_t)b * Hh * Tt;

    const int qrow = q0 + wq * 16 + l15;
    s16x8 qf[4];
#pragma unroll
    for (int ks = 0; ks < 4; ++ks)
        qf[ks] = *reinterpret_cast<const s16x8*>(
            &qb[(size_t)qrow * Hh + ks * 32 + l4 * 8]);

    f32x4 o[8];
#pragma unroll
    for (int nh = 0; nh < 8; ++nh) { f32x4 z4 = {0.f,0.f,0.f,0.f}; o[nh] = z4; }
    float mreg = -1e30f, lreg = 0.f;

    const int kr_s  = tid >> 2, kc_s = (tid & 3) * 4;
    const int vh_s  = tid >> 1, vc_s = (tid & 1) * 4;
    u16* ps = psl + wid * 640;

    for (int j = lo; j < hi; ++j) {
        const int kv0 = j * 64;

#pragma unroll
        for (int i = 0; i < 4; ++i) {
            s16x8 tk = *reinterpret_cast<const s16x8*>(
                &kb[(size_t)(kv0 + kr_s) * Hh + (kc_s + i) * 8]);
            *reinterpret_cast<s16x8*>(
                &ksl[kr_s * 128 + (((kc_s + i) * 8) ^ ((kr_s & 7) << 3))]) = tk;
        }
#pragma unroll
        for (int i = 0; i < 4; ++i) {
            s16x8 tv = *reinterpret_cast<const s16x8*>(
                &vb[(size_t)vh_s * Tt + kv0 + (vc_s + i) * 8]);
            *reinterpret_cast<s16x8*>(
                &vsl[vh_s * 64 + (((vc_s + i) * 8) ^ ((vh_s & 7) << 3))]) = tv;
        }
        __syncthreads();

        f32x4 sacc[2];
#pragma unroll
        for (int nf = 0; nf < 2; ++nf) { f32x4 z4 = {0.f,0.f,0.f,0.f}; sacc[nf] = z4; }
#pragma unroll
        for (int nf = 0; nf < 2; ++nf) {
            const int kr = half * 32 + nf * 16 + l15;
#pragma unroll
            for (int ks = 0; ks < 4; ++ks) {
                s16x8 kfrag = *reinterpret_cast<const s16x8*>(
                    &ksl[kr * 128 + ((ks * 32 + l4 * 8) ^ ((kr & 7) << 3))]);
                sacc[nf] = __builtin_amdgcn_mfma_f32_16x16x32_bf16(
                    kfrag, qf[ks], sacc[nf], 0, 0, 0);
            }
        }

        const bool diag = (j == ntf - 1);
        float pv2[2][4];
#pragma unroll
        for (int nf = 0; nf < 2; ++nf)
#pragma unroll
            for (int r = 0; r < 4; ++r) {
                float s = sacc[nf][r] * kScale;
                if (diag) {
                    int kvg = kv0 + half * 32 + nf * 16 + l4 * 4 + r;
                    if (kvg > qrow) s = -1e30f;
                }
                pv2[nf][r] = s;
            }
        float mx = fmaxf(fmaxf(fmaxf(pv2[0][0], pv2[0][1]), fmaxf(pv2[0][2], pv2[0][3])),
                         fmaxf(fmaxf(pv2[1][0], pv2[1][1]), fmaxf(pv2[1][2], pv2[1][3])));
        mx = fmaxf(mx, __shfl_xor(mx, 16));
        mx = fmaxf(mx, __shfl_xor(mx, 32));
        const float mold = mreg;
        const float mnew = fmaxf(mold, mx);
        const float scl = __expf(mold - mnew);
        mreg = mnew;
        float rs = 0.f;
#pragma unroll
        for (int nf = 0; nf < 2; ++nf)
#pragma unroll
            for (int r = 0; r < 4; ++r) {
                float pp = __expf(pv2[nf][r] - mnew);
                pv2[nf][r] = pp; rs += pp;
            }
        rs += __shfl_xor(rs, 16);
        rs += __shfl_xor(rs, 32);
        lreg = lreg * scl + rs;

        if (!__all(mold == mnew)) {
            float sclr[4];
#pragma unroll
            for (int r = 0; r < 4; ++r) sclr[r] = __shfl(scl, l4 * 4 + r);
#pragma unroll
            for (int nh = 0; nh < 8; ++nh)
#pragma unroll
                for (int r = 0; r < 4; ++r) o[nh][r] *= sclr[r];
        }

#pragma unroll
        for (int nf = 0; nf < 2; ++nf) {
            s16x4 pk4;
#pragma unroll
            for (int r = 0; r < 4; ++r) pk4[r] = (short)f2bf(pv2[nf][r]);
            *reinterpret_cast<s16x4*>(&ps[l15 * 40 + nf * 16 + l4 * 4]) = pk4;
        }
        s16x8 pa = *reinterpret_cast<const s16x8*>(&ps[l15 * 40 + l4 * 8]);

#pragma unroll
        for (int nh = 0; nh < 8; ++nh) {
            const int hr = nh * 16 + l15;
            s16x8 vfrag = *reinterpret_cast<const s16x8*>(
                &vsl[hr * 64 + ((half * 32 + l4 * 8) ^ ((hr & 7) << 3))]);
            o[nh] = __builtin_amdgcn_mfma_f32_16x16x32_bf16(
                pa, vfrag, o[nh], 0, 0, 0);
        }
        __syncthreads();
    }

#pragma unroll
    for (int nh = 0; nh < 8; ++nh)
#pragma unroll
        for (int r = 0; r < 4; ++r)
            Om[((wid * 16) + l4 * 4 + r) * 132 + nh * 16 + l15] = o[nh][r];
    if (lane < 16) {
        ml2[wid * 32 + lane] = mreg;
        ml2[wid * 32 + 16 + lane] = lreg;
    }
    __syncthreads();

    {
        const int row = tid >> 3, ch = tid & 7;
        const int rg = row >> 4, r16 = row & 15;
        const int w0 = rg * 2, w1 = rg * 2 + 1;
        float m0v = ml2[w0 * 32 + r16], m1v = ml2[w1 * 32 + r16];
        float M = fmaxf(m0v, m1v);
        float f0 = __expf(m0v - M), f1 = __expf(m1v - M);
        float L = f0 * ml2[w0 * 32 + 16 + r16] + f1 * ml2[w1 * 32 + 16 + r16];
        const size_t gm = (size_t)b * Tt + q0 + row;
        union { u16 u[8]; s16x8 v; } pk0, pk1;
#pragma unroll
        for (int c = 0; c < 8; ++c) {
            float a = f0 * Om[(w0 * 16 + r16) * 132 + ch * 16 + c]
                    + f1 * Om[(w1 * 16 + r16) * 132 + ch * 16 + c];
            pk0.u[c] = f2bf(a);
        }
#pragma unroll
        for (int c = 0; c < 8; ++c) {
            float a = f0 * Om[(w0 * 16 + r16) * 132 + ch * 16 + 8 + c]
                    + f1 * Om[(w1 * 16 + r16) * 132 + ch * 16 + 8 + c];
            pk1.u[c] = f2bf(a);
        }
        u16* op = Opart + ((size_t)split * Mrows + gm) * 128 + ch * 16;
        *reinterpret_cast<s16x8*>(op) = pk0.v;
        *reinterpret_cast<s16x8*>(op + 8) = pk1.v;
        if (ch == 0) {
            Mp[split * Mrows + gm] = M;
            Lp[split * Mrows + gm] = L;
        }
    }
}

// ---------------------------------------------------------------------------
// Kernel 3: merge 2 KV-split partials + fused output projection + bias.
// (verbatim round-11/12/13 version)
// ---------------------------------------------------------------------------
__global__ __launch_bounds__(256) void merge_proj(
    const u16* __restrict__ Opart, const float* __restrict__ Mp,
    const float* __restrict__ Lp, const u16* __restrict__ wpt,
    const float* __restrict__ bp, float* __restrict__ O)
{
    __shared__ __align__(16) u16 pm[64 * 136];
    __shared__ float f0s[64], f1s[64], invs[64];

    const int tid = threadIdx.x, lane = tid & 63, wid = tid >> 6;
    const int l15 = lane & 15, l4 = lane >> 4;
    const int m0r = blockIdx.x * 64;

    if (tid < 64) {
        float m0v = Mp[m0r + tid], m1v = Mp[Mrows + m0r + tid];
        float M = fmaxf(m0v, m1v);
        float a0 = __expf(m0v - M), a1 = __expf(m1v - M);
        float L = a0 * Lp[m0r + tid] + a1 * Lp[Mrows + m0r + tid];
        f0s[tid] = a0; f1s[tid] = a1; invs[tid] = 1.f / L;
    }
    __syncthreads();

#pragma unroll
    for (int u = 0; u < 4; ++u) {
        int idx = tid + u * 256;
        int row = idx >> 4, g = idx & 15;
        const size_t base = (size_t)(m0r + row) * 128 + g * 8;
        s16x8 p0 = *reinterpret_cast<const s16x8*>(&Opart[base]);
        s16x8 p1 = *reinterpret_cast<const s16x8*>(
            &Opart[(size_t)Mrows * 128 + base]);
        float a0 = f0s[row], a1 = f1s[row], inv = invs[row];
        union { u16 u[8]; s16x8 v; } pk;
#pragma unroll
        for (int c = 0; c < 8; ++c) {
            float v0 = bf2f((u16)p0[c]), v1 = bf2f((u16)p1[c]);
            pk.u[c] = f2bf((a0 * v0 + a1 * v1) * inv);
        }
        *reinterpret_cast<s16x8*>(&pm[row * 136 + g * 8]) = pk.v;
    }
    __syncthreads();

    {
        const int row2 = wid * 16 + l15;
        s16x8 af2[4];
#pragma unroll
        for (int ks = 0; ks < 4; ++ks)
            af2[ks] = *reinterpret_cast<const s16x8*>(
                &pm[row2 * 136 + ks * 32 + l4 * 8]);
#pragma unroll
        for (int ng = 0; ng < 8; ++ng) {
            const int ncol = ng * 16 + l15;
            f32x4 pacc = {0.f, 0.f, 0.f, 0.f};
#pragma unroll
            for (int ks = 0; ks < 4; ++ks) {
                s16x8 wf = *reinterpret_cast<const s16x8*>(
                    &wpt[(size_t)ncol * 128 + ks * 32 + l4 * 8]);
                pacc = __builtin_amdgcn_mfma_f32_16x16x32_bf16(
                    af2[ks], wf, pacc, 0, 0, 0);
            }
            float bias = bp[ncol];
#pragma unroll
            for (int r = 0; r < 4; ++r)
                O[(size_t)(m0r + wid * 16 + l4 * 4 + r) * Hh + ncol] =
                    pacc[r] + bias;
        }
    }
}

// ---------------------------------------------------------------------------
extern "C" void kernel_launch(void* const* d_in, const int* in_sizes, int n_in,
                              void* d_out, int out_size, void* d_ws, size_t ws_size,
                              hipStream_t stream) {
    const float* x  = (const float*)d_in[0];
    const float* Wk = (const float*)d_in[1];
    const float* Wq = (const float*)d_in[2];
    const float* Wv = (const float*)d_in[3];
    const float* Wp = (const float*)d_in[4];
    const float* bp = (const float*)d_in[5];
    float* out = (float*)d_out;

    // workspace (u16): wt 393216 | wpt 16384 | qw 2M | kw 2M | vt 2M |
    //                  Opart 2x2M | Mp,Lp f32 2x16384 each   (~22.1 MB)
    u16* wtb = (u16*)d_ws;
    u16* wpt = wtb + 393216;
    u16* qw  = wpt + 16384;
    u16* kw  = qw + (size_t)Mrows * Hh;
    u16* vtb = kw + (size_t)Mrows * Hh;
    u16* opart = vtb + (size_t)Mrows * Hh;
    float* Mpart = (float*)(opart + (size_t)2 * Mrows * Hh);
    float* Lpart = Mpart + 2 * Mrows;

    convw_kernel<<<1600, 256, 0, stream>>>(Wq, Wk, Wv, Wp, wtb, wpt);
    qkv_fused<<<dim3(Mrows / 64, 1, 3), 256, 0, stream>>>(x, wtb, qw, kw, vtb);
    attn_kernel<<<1024, 256, 0, stream>>>(qw, kw, vtb, opart, Mpart, Lpart);
    merge_proj<<<Mrows / 64, 256, 0, stream>>>(opart, Mpart, Lpart, wpt, bp, out);
}